// Round 7
// baseline (231.653 us; speedup 1.0000x reference)
//
#include <hip/hip_runtime.h>
#include <cfloat>

// Problem constants: M=N=64 grid, DIM=512, B=4096, SIGMA=32
#define DIMK 512
#define MN   4096
#define BATCH 4096
#define BK 32
#define NCHUNK 64   // per-row argmin partials: 64 chunks of 64 cols

typedef _Float16 half8_t __attribute__((ext_vector_type(8)));
typedef _Float16 half4_t __attribute__((ext_vector_type(4)));
typedef float f32x4 __attribute__((ext_vector_type(4)));

// ---------------------------------------------------------------------------
// fp32 -> (hi, mid) f16 split: a = hi + mid + O(2^-22 |a|).
// Blocks < 2048 convert X; blocks >= 2048 convert W AND compute w2 row sums
// (each block covers exactly 2 rows of 512).
// ---------------------------------------------------------------------------
__global__ __launch_bounds__(256) void convert_kernel(
        const float* __restrict__ X, const float* __restrict__ W,
        _Float16* __restrict__ Xhi, _Float16* __restrict__ Xmi,
        _Float16* __restrict__ Whi, _Float16* __restrict__ Wmi,
        float* __restrict__ w2) {
    const int blk = blockIdx.x;
    const int t   = threadIdx.x;
    const bool isW = blk >= 2048;
    const float* src = isW ? W : X;
    _Float16* hi  = isW ? Whi : Xhi;
    _Float16* mid = isW ? Wmi : Xmi;
    const size_t base = (size_t)(isW ? blk - 2048 : blk) * 1024;
    const size_t idx  = base + (size_t)t * 4;
    float4 v = *(const float4*)(src + idx);
    _Float16 h0 = (_Float16)v.x, h1 = (_Float16)v.y,
             h2 = (_Float16)v.z, h3 = (_Float16)v.w;
    half4_t hv = {h0, h1, h2, h3};
    half4_t mv = {(_Float16)(v.x - (float)h0), (_Float16)(v.y - (float)h1),
                  (_Float16)(v.z - (float)h2), (_Float16)(v.w - (float)h3)};
    *(half4_t*)(hi + idx) = hv;
    *(half4_t*)(mid + idx) = mv;
    if (isW) {
        __shared__ float ws[4];
        float s = v.x*v.x + v.y*v.y + v.z*v.z + v.w*v.w;
        int lane = t & 63;
#pragma unroll
        for (int o = 32; o > 0; o >>= 1) s += __shfl_down(s, o);
        if (lane == 0) ws[t >> 6] = s;
        __syncthreads();
        size_t row = base >> 9;          // (blk-2048)*2
        if (t == 0)   w2[row]     = ws[0] + ws[1];
        if (t == 128) w2[row + 1] = ws[2] + ws[3];
    }
}

// ---------------------------------------------------------------------------
// Barrier-free MFMA score kernel: s[b,k] = w2[k] - 2*dot(X[b],W[k]) via
// 3-product f16 hi/mid split. NO LDS, NO __syncthreads in the K-loop:
// each wave owns a private 64x64 quadrant (block = 4 waves in 2x2) and loads
// BOTH A and B fragments global->VGPR directly — the MFMA A/B fragment layout
// (row = lane&15, k = (lane>>4)*8+e) is a clean 16B/lane global load.
// Register double-buffered (cur/next); waves slip freely, 2 waves/SIMD cover
// each other's L2 latency with MFMA phases. Co-resident waves sharing m- or
// n-ranges hit L1 on the duplicated lines.
// ---------------------------------------------------------------------------
__global__ __launch_bounds__(256, 2) void score_kernel(
        const _Float16* __restrict__ Xhi, const _Float16* __restrict__ Xmi,
        const _Float16* __restrict__ Whi, const _Float16* __restrict__ Wmi,
        const float* __restrict__ w2,
        float* __restrict__ pval, int* __restrict__ pidx) {
    const int t    = threadIdx.x;
    const int lane = t & 63;
    const int w    = t >> 6;
    const int wm   = w >> 1;
    const int wn   = w & 1;
    const int m0   = blockIdx.y * 128 + wm * 64;   // this wave's 64-row base
    const int n0   = blockIdx.x * 128 + wn * 64;   // this wave's 64-col base
    const int r16  = lane & 15;
    const int oct  = lane >> 4;     // k-octet 0..3

    f32x4 acc[4][4];
#pragma unroll
    for (int i = 0; i < 4; i++)
#pragma unroll
        for (int j = 0; j < 4; j++) acc[i][j] = (f32x4){0.f, 0.f, 0.f, 0.f};

    // fragment base pointers (k-offset oct*8 baked in)
    const _Float16 *gAh[4], *gAm[4], *gBh[4], *gBm[4];
#pragma unroll
    for (int i = 0; i < 4; i++) {
        size_t aoff = (size_t)(m0 + i * 16 + r16) * DIMK + oct * 8;
        gAh[i] = Xhi + aoff;
        gAm[i] = Xmi + aoff;
        size_t boff = (size_t)(n0 + i * 16 + r16) * DIMK + oct * 8;
        gBh[i] = Whi + boff;
        gBm[i] = Wmi + boff;
    }

    // prologue: k=0 fragments
    half8_t ahc[4], amc[4], bhc[4], bmc[4];
#pragma unroll
    for (int i = 0; i < 4; i++) {
        ahc[i] = *(const half8_t*)(gAh[i]);
        amc[i] = *(const half8_t*)(gAm[i]);
        bhc[i] = *(const half8_t*)(gBh[i]);
        bmc[i] = *(const half8_t*)(gBm[i]);
    }

#pragma unroll 2
    for (int k0 = 0; k0 < DIMK; k0 += BK) {
        const bool more = (k0 + BK) < DIMK;
        const int  nk   = more ? (k0 + BK) : 0;   // last-iter prefetch discarded
        // next-iter fragments (in flight during this iter's 48 MFMAs)
        half8_t ahn[4], amn[4], bhn[4], bmn[4];
#pragma unroll
        for (int i = 0; i < 4; i++) {
            ahn[i] = *(const half8_t*)(gAh[i] + nk);
            amn[i] = *(const half8_t*)(gAm[i] + nk);
            bhn[i] = *(const half8_t*)(gBh[i] + nk);
            bmn[i] = *(const half8_t*)(gBm[i] + nk);
        }
        // 48 MFMA on current fragments
#pragma unroll
        for (int i = 0; i < 4; i++)
#pragma unroll
            for (int j = 0; j < 4; j++) {
                acc[i][j] = __builtin_amdgcn_mfma_f32_16x16x32_f16(amc[i], bhc[j], acc[i][j], 0, 0, 0);
                acc[i][j] = __builtin_amdgcn_mfma_f32_16x16x32_f16(ahc[i], bmc[j], acc[i][j], 0, 0, 0);
                acc[i][j] = __builtin_amdgcn_mfma_f32_16x16x32_f16(ahc[i], bhc[j], acc[i][j], 0, 0, 0);
            }
        // rotate
#pragma unroll
        for (int i = 0; i < 4; i++) {
            ahc[i] = ahn[i]; amc[i] = amn[i];
            bhc[i] = bhn[i]; bmc[i] = bmn[i];
        }
    }

    // ---- per-row argmin over this wave's 64 cols ----
    // D layout: col = lane&15, row = (lane>>4)*4 + v   (m89/m91 verified)
    float w2v[4];
    int   ncol[4];
#pragma unroll
    for (int j = 0; j < 4; j++) {
        ncol[j] = n0 + j * 16 + r16;
        w2v[j]  = w2[ncol[j]];
    }
#pragma unroll
    for (int i = 0; i < 4; i++)
#pragma unroll
        for (int v = 0; v < 4; v++) {
            float bv = FLT_MAX;
            int   bi = 0x7FFFFFFF;
#pragma unroll
            for (int j = 0; j < 4; j++) {        // j ascending -> ties keep lower n
                float s = w2v[j] - 2.0f * acc[i][j][v];
                if (s < bv) { bv = s; bi = ncol[j]; }
            }
#pragma unroll
            for (int mask = 1; mask <= 8; mask <<= 1) {   // reduce over 16 col-lanes
                float ov = __shfl_xor(bv, mask);
                int   oi = __shfl_xor(bi, mask);
                if (ov < bv || (ov == bv && oi < bi)) { bv = ov; bi = oi; }
            }
            if (r16 == 0) {
                int m = m0 + i * 16 + oct * 4 + v;
                int chunk = n0 >> 6;
                pval[(size_t)m * NCHUNK + chunk] = bv;
                pidx[(size_t)m * NCHUNK + chunk] = bi;
            }
        }
}

// ---------------------------------------------------------------------------
// Final: reduce 64 partials/row -> BMU, separable Gaussian, write 4096 floats.
// ---------------------------------------------------------------------------
__global__ __launch_bounds__(256) void epilogue_kernel(
        const float* __restrict__ pval, const int* __restrict__ pidx,
        const int* __restrict__ decay_p, const int* __restrict__ it_p,
        float* __restrict__ out) {
    __shared__ float er[64];
    __shared__ float ec[64];
    __shared__ int   s_idx;
    const int b = blockIdx.x;
    const int t = threadIdx.x;

    if (t < 64) {
        float v  = pval[(size_t)b * NCHUNK + t];
        int   ii = pidx[(size_t)b * NCHUNK + t];
#pragma unroll
        for (int mask = 1; mask <= 32; mask <<= 1) {
            float ov = __shfl_xor(v, mask);
            int   oi = __shfl_xor(ii, mask);
            if (ov < v || (ov == v && oi < ii)) { v = ov; ii = oi; }
        }
        if (t == 0) s_idx = ii;
    }
    __syncthreads();
    const int r = s_idx >> 6;
    const int c = s_idx & 63;
    const float lr  = expf(-(float)(*it_p) / (float)(*decay_p));
    const float so  = 32.0f * lr;          // SIGMA = 32
    const float inv = 1.0f / (so * so);
    if (t < 64) {
        float d = (float)(t - r);
        er[t] = expf(-d * d * inv);
    } else if (t < 128) {
        int j = t - 64;
        float d = (float)(j - c);
        ec[j] = expf(-d * d * inv);
    }
    __syncthreads();
    float4* out4 = (float4*)(out + (size_t)b * 4096);
#pragma unroll
    for (int qq = 0; qq < 4; qq++) {
        int f  = t + 256 * qq;
        int i  = f >> 4;
        int j0 = (f & 15) * 4;
        float e = er[i];
        out4[f] = make_float4(e * ec[j0], e * ec[j0 + 1],
                              e * ec[j0 + 2], e * ec[j0 + 3]);
    }
}

// ---------------------------------------------------------------------------
extern "C" void kernel_launch(void* const* d_in, const int* in_sizes, int n_in,
                              void* d_out, int out_size, void* d_ws, size_t ws_size,
                              hipStream_t stream) {
    const float* X       = (const float*)d_in[0];   // [4096,512]
    const float* W       = (const float*)d_in[1];   // [4096,512]
    const int*   decay_p = (const int*)d_in[3];
    const int*   it_p    = (const int*)d_in[4];
    float* out = (float*)d_out;

    // ws: Xhi|Xmi|Whi|Wmi (4MB each f16) | w2 16KB | pval 1MB | pidx 1MB
    _Float16* Xhi = (_Float16*)d_ws;
    _Float16* Xmi = Xhi + (size_t)BATCH * DIMK;
    _Float16* Whi = Xmi + (size_t)BATCH * DIMK;
    _Float16* Wmi = Whi + (size_t)MN * DIMK;
    float*    w2  = (float*)(Wmi + (size_t)MN * DIMK);
    float*    pval = w2 + MN;
    int*      pidx = (int*)(pval + (size_t)BATCH * NCHUNK);

    convert_kernel<<<4096, 256, 0, stream>>>(X, W, Xhi, Xmi, Whi, Wmi, w2);
    score_kernel<<<dim3(32, 32), 256, 0, stream>>>(Xhi, Xmi, Whi, Wmi, w2, pval, pidx);
    epilogue_kernel<<<BATCH, 256, 0, stream>>>(pval, pidx, decay_p, it_p, out);
}

// Round 8
// 172.742 us; speedup vs baseline: 1.3410x; 1.3410x over previous
//
#include <hip/hip_runtime.h>
#include <cfloat>

// Problem constants: M=N=64 grid, DIM=512, B=4096, SIGMA=32
#define DIMK 512
#define MN   4096
#define BATCH 4096
#define BK 32
#define NCHUNK 64   // per-row argmin partials: 64 chunks of 64 cols

typedef _Float16 half8_t __attribute__((ext_vector_type(8)));
typedef float f32x4 __attribute__((ext_vector_type(4)));

// async global->LDS, 16B per lane; LDS dest is wave-uniform base + lane*16
#define GLD16(gp, lp) __builtin_amdgcn_global_load_lds( \
    (const __attribute__((address_space(1))) void*)(gp), \
    (__attribute__((address_space(3))) void*)(lp), 16, 0, 0)

// ---------------------------------------------------------------------------
// fp32 -> (hi, mid) f16 split: a = hi + mid + O(2^-22 |a|).
// 2048 blocks: [0,1024) convert X, [1024,2048) convert W + w2 row sums.
// 8 floats/thread: 2x float4 loads, 2x 16B half8 stores (fully coalesced).
// For W, one wave == one 512-float row -> w2 by pure shuffle reduce.
// ---------------------------------------------------------------------------
__global__ __launch_bounds__(256) void convert_kernel(
        const float* __restrict__ X, const float* __restrict__ W,
        _Float16* __restrict__ Xhi, _Float16* __restrict__ Xmi,
        _Float16* __restrict__ Whi, _Float16* __restrict__ Wmi,
        float* __restrict__ w2) {
    const int blk  = blockIdx.x;
    const int t    = threadIdx.x;
    const bool isW = blk >= 1024;
    const float* src = isW ? W : X;
    _Float16* hi  = isW ? Whi : Xhi;
    _Float16* mid = isW ? Wmi : Xmi;
    const size_t idx = (size_t)(isW ? blk - 1024 : blk) * 2048 + (size_t)t * 8;

    float4 v0 = *(const float4*)(src + idx);
    float4 v1 = *(const float4*)(src + idx + 4);
    float v[8] = {v0.x, v0.y, v0.z, v0.w, v1.x, v1.y, v1.z, v1.w};
    half8_t hv, mv;
    float s = 0.f;
#pragma unroll
    for (int e = 0; e < 8; e++) {
        s += v[e] * v[e];
        _Float16 h = (_Float16)v[e];
        hv[e] = h;
        mv[e] = (_Float16)(v[e] - (float)h);
    }
    *(half8_t*)(hi + idx) = hv;
    *(half8_t*)(mid + idx) = mv;

    if (isW) {
        // one wave covers exactly one row of 512: reduce s across 64 lanes
#pragma unroll
        for (int o = 32; o > 0; o >>= 1) s += __shfl_down(s, o);
        if ((t & 63) == 0) {
            int row = (blk - 1024) * 4 + (t >> 6);
            w2[row] = s;
        }
    }
}

// ---------------------------------------------------------------------------
// MFMA score kernel (R3 structure — best measured: 87.6 us):
// s[b,k] = w2[k] - 2*dot(X[b],W[k]) via 3-product f16 hi/mid split.
// 128x128 tile, BK=32, double-buffered LDS (64KB), ONE barrier per K-iter:
// prefetch tile k+1 into the alternate buffer immediately after the barrier,
// then compute on tile k — the vmcnt drain at the next barrier finds the
// prefetch already complete (issued a full MFMA phase earlier).
// ---------------------------------------------------------------------------
__global__ __launch_bounds__(256, 2) void score_kernel(
        const _Float16* __restrict__ Xhi, const _Float16* __restrict__ Xmi,
        const _Float16* __restrict__ Whi, const _Float16* __restrict__ Wmi,
        const float* __restrict__ w2,
        float* __restrict__ pval, int* __restrict__ pidx) {
    // 64 KB: two buffers, each Ah|Am|Bh|Bm (4096 f16 = 8KB each)
    __shared__ __align__(16) _Float16 lds[2][16384];

    const int t    = threadIdx.x;
    const int lane = t & 63;
    const int w    = t >> 6;        // wave 0..3
    const int wm   = w >> 1;        // wave m-half
    const int wn   = w & 1;         // wave n-half
    const int m0   = blockIdx.y * 128;
    const int n0   = blockIdx.x * 128;

    f32x4 acc[4][4];
#pragma unroll
    for (int i = 0; i < 4; i++)
#pragma unroll
        for (int j = 0; j < 4; j++) acc[i][j] = (f32x4){0.f, 0.f, 0.f, 0.f};

    // staging: wave w loads 16-row blocks (2w, 2w+1) of each of the 4 arrays.
    // within a 1KB block: lane l -> row (l&15), k-octet (l>>4).
    const int r16 = lane & 15;
    const int kg  = lane >> 4;
    const int b0  = 2 * w, b1 = 2 * w + 1;
    const size_t ko = (size_t)kg * 8;
    const _Float16* gA[4];
    const _Float16* gB[4];
    gA[0] = Xhi + (size_t)(m0 + b0 * 16 + r16) * DIMK + ko;
    gA[1] = Xhi + (size_t)(m0 + b1 * 16 + r16) * DIMK + ko;
    gA[2] = Xmi + (size_t)(m0 + b0 * 16 + r16) * DIMK + ko;
    gA[3] = Xmi + (size_t)(m0 + b1 * 16 + r16) * DIMK + ko;
    gB[0] = Whi + (size_t)(n0 + b0 * 16 + r16) * DIMK + ko;
    gB[1] = Whi + (size_t)(n0 + b1 * 16 + r16) * DIMK + ko;
    gB[2] = Wmi + (size_t)(n0 + b0 * 16 + r16) * DIMK + ko;
    gB[3] = Wmi + (size_t)(n0 + b1 * 16 + r16) * DIMK + ko;
    // LDS dest offsets (f16 units) within a buffer: Ah@0 Am@4096 Bh@8192 Bm@12288
    const int dA[4] = {b0 * 512, b1 * 512, 4096 + b0 * 512, 4096 + b1 * 512};
    const int dB[4] = {8192 + b0 * 512, 8192 + b1 * 512,
                       12288 + b0 * 512, 12288 + b1 * 512};

    // prologue: fill buffer 0 with tile k=0
#pragma unroll
    for (int p = 0; p < 4; p++) {
        GLD16(gA[p], &lds[0][dA[p]]);
        GLD16(gB[p], &lds[0][dB[p]]);
    }

    int cur = 0;
    for (int k0 = 0; k0 < DIMK; k0 += BK) {
        __syncthreads();               // lds[cur] staged; prior frag reads done
        if (k0 + BK < DIMK) {          // prefetch next tile into alternate buf
            int nk = k0 + BK;
#pragma unroll
            for (int p = 0; p < 4; p++) {
                GLD16(gA[p] + nk, &lds[cur ^ 1][dA[p]]);
                GLD16(gB[p] + nk, &lds[cur ^ 1][dB[p]]);
            }
        }
        const _Float16* sAh = &lds[cur][0];
        const _Float16* sAm = &lds[cur][4096];
        const _Float16* sBh = &lds[cur][8192];
        const _Float16* sBm = &lds[cur][12288];

        half8_t ah[4], am[4], bh[4], bm[4];
#pragma unroll
        for (int i = 0; i < 4; i++) {
            ah[i] = *(const half8_t*)(sAh + (wm * 4 + i) * 512 + lane * 8);
            am[i] = *(const half8_t*)(sAm + (wm * 4 + i) * 512 + lane * 8);
            bh[i] = *(const half8_t*)(sBh + (wn * 4 + i) * 512 + lane * 8);
            bm[i] = *(const half8_t*)(sBm + (wn * 4 + i) * 512 + lane * 8);
        }
#pragma unroll
        for (int i = 0; i < 4; i++)
#pragma unroll
            for (int j = 0; j < 4; j++) {
                acc[i][j] = __builtin_amdgcn_mfma_f32_16x16x32_f16(am[i], bh[j], acc[i][j], 0, 0, 0);
                acc[i][j] = __builtin_amdgcn_mfma_f32_16x16x32_f16(ah[i], bm[j], acc[i][j], 0, 0, 0);
                acc[i][j] = __builtin_amdgcn_mfma_f32_16x16x32_f16(ah[i], bh[j], acc[i][j], 0, 0, 0);
            }
        cur ^= 1;
    }

    // ---- per-row argmin over this wave's 64 cols ----
    // D layout: col = lane&15, row = (lane>>4)*4 + v   (m89/m91 verified)
    const int q  = lane >> 4;
    const int cl = lane & 15;
    float w2v[4];
    int   ncol[4];
#pragma unroll
    for (int j = 0; j < 4; j++) {
        ncol[j] = n0 + wn * 64 + j * 16 + cl;
        w2v[j]  = w2[ncol[j]];
    }
#pragma unroll
    for (int i = 0; i < 4; i++)
#pragma unroll
        for (int v = 0; v < 4; v++) {
            float bv = FLT_MAX;
            int   bi = 0x7FFFFFFF;
#pragma unroll
            for (int j = 0; j < 4; j++) {        // j ascending -> ties keep lower n
                float s = w2v[j] - 2.0f * acc[i][j][v];
                if (s < bv) { bv = s; bi = ncol[j]; }
            }
#pragma unroll
            for (int mask = 1; mask <= 8; mask <<= 1) {   // reduce over 16 col-lanes
                float ov = __shfl_xor(bv, mask);
                int   oi = __shfl_xor(bi, mask);
                if (ov < bv || (ov == bv && oi < bi)) { bv = ov; bi = oi; }
            }
            if (cl == 0) {
                int m = m0 + wm * 64 + i * 16 + q * 4 + v;
                int chunk = blockIdx.x * 2 + wn;
                pval[(size_t)m * NCHUNK + chunk] = bv;
                pidx[(size_t)m * NCHUNK + chunk] = bi;
            }
        }
}

// ---------------------------------------------------------------------------
// Final: reduce 64 partials/row -> BMU, separable Gaussian, write 4096 floats.
// ---------------------------------------------------------------------------
__global__ __launch_bounds__(256) void epilogue_kernel(
        const float* __restrict__ pval, const int* __restrict__ pidx,
        const int* __restrict__ decay_p, const int* __restrict__ it_p,
        float* __restrict__ out) {
    __shared__ float er[64];
    __shared__ float ec[64];
    __shared__ int   s_idx;
    const int b = blockIdx.x;
    const int t = threadIdx.x;

    if (t < 64) {
        float v  = pval[(size_t)b * NCHUNK + t];
        int   ii = pidx[(size_t)b * NCHUNK + t];
#pragma unroll
        for (int mask = 1; mask <= 32; mask <<= 1) {
            float ov = __shfl_xor(v, mask);
            int   oi = __shfl_xor(ii, mask);
            if (ov < v || (ov == v && oi < ii)) { v = ov; ii = oi; }
        }
        if (t == 0) s_idx = ii;
    }
    __syncthreads();
    const int r = s_idx >> 6;
    const int c = s_idx & 63;
    const float lr  = expf(-(float)(*it_p) / (float)(*decay_p));
    const float so  = 32.0f * lr;          // SIGMA = 32
    const float inv = 1.0f / (so * so);
    if (t < 64) {
        float d = (float)(t - r);
        er[t] = expf(-d * d * inv);
    } else if (t < 128) {
        int j = t - 64;
        float d = (float)(j - c);
        ec[j] = expf(-d * d * inv);
    }
    __syncthreads();
    float4* out4 = (float4*)(out + (size_t)b * 4096);
#pragma unroll
    for (int qq = 0; qq < 4; qq++) {
        int f  = t + 256 * qq;
        int i  = f >> 4;
        int j0 = (f & 15) * 4;
        float e = er[i];
        out4[f] = make_float4(e * ec[j0], e * ec[j0 + 1],
                              e * ec[j0 + 2], e * ec[j0 + 3]);
    }
}

// ---------------------------------------------------------------------------
extern "C" void kernel_launch(void* const* d_in, const int* in_sizes, int n_in,
                              void* d_out, int out_size, void* d_ws, size_t ws_size,
                              hipStream_t stream) {
    const float* X       = (const float*)d_in[0];   // [4096,512]
    const float* W       = (const float*)d_in[1];   // [4096,512]
    const int*   decay_p = (const int*)d_in[3];
    const int*   it_p    = (const int*)d_in[4];
    float* out = (float*)d_out;

    // ws: Xhi|Xmi|Whi|Wmi (4MB each f16) | w2 16KB | pval 1MB | pidx 1MB
    _Float16* Xhi = (_Float16*)d_ws;
    _Float16* Xmi = Xhi + (size_t)BATCH * DIMK;
    _Float16* Whi = Xmi + (size_t)BATCH * DIMK;
    _Float16* Wmi = Whi + (size_t)MN * DIMK;
    float*    w2  = (float*)(Wmi + (size_t)MN * DIMK);
    float*    pval = w2 + MN;
    int*      pidx = (int*)(pval + (size_t)BATCH * NCHUNK);

    convert_kernel<<<2048, 256, 0, stream>>>(X, W, Xhi, Xmi, Whi, Wmi, w2);
    score_kernel<<<dim3(32, 32), 256, 0, stream>>>(Xhi, Xmi, Whi, Wmi, w2, pval, pidx);
    epilogue_kernel<<<BATCH, 256, 0, stream>>>(pval, pidx, decay_p, it_p, out);
}

// Round 9
// 172.741 us; speedup vs baseline: 1.3410x; 1.0000x over previous
//
#include <hip/hip_runtime.h>
#include <cfloat>

// Problem constants: M=N=64 grid, DIM=512, B=4096, SIGMA=32
#define DIMK 512
#define MN   4096
#define BATCH 4096
#define BK 32
#define NCHUNK 64   // per-row argmin partials: 64 chunks of 64 cols

typedef _Float16 half8_t __attribute__((ext_vector_type(8)));
typedef float f32x4 __attribute__((ext_vector_type(4)));

// async global->LDS, 16B per lane; LDS dest is wave-uniform base + lane*16
#define GLD16(gp, lp) __builtin_amdgcn_global_load_lds( \
    (const __attribute__((address_space(1))) void*)(gp), \
    (__attribute__((address_space(3))) void*)(lp), 16, 0, 0)

// ---------------------------------------------------------------------------
// fp32 -> (hi, mid) f16 split: a = hi + mid + O(2^-22 |a|).
// 2048 blocks: [0,1024) convert X, [1024,2048) convert W + w2 row sums.
// 8 floats/thread: 2x float4 loads, 2x 16B half8 stores (fully coalesced).
// For W, one wave == one 512-float row -> w2 by pure shuffle reduce.
// ---------------------------------------------------------------------------
__global__ __launch_bounds__(256) void convert_kernel(
        const float* __restrict__ X, const float* __restrict__ W,
        _Float16* __restrict__ Xhi, _Float16* __restrict__ Xmi,
        _Float16* __restrict__ Whi, _Float16* __restrict__ Wmi,
        float* __restrict__ w2) {
    const int blk  = blockIdx.x;
    const int t    = threadIdx.x;
    const bool isW = blk >= 1024;
    const float* src = isW ? W : X;
    _Float16* hi  = isW ? Whi : Xhi;
    _Float16* mid = isW ? Wmi : Xmi;
    const size_t idx = (size_t)(isW ? blk - 1024 : blk) * 2048 + (size_t)t * 8;

    float4 v0 = *(const float4*)(src + idx);
    float4 v1 = *(const float4*)(src + idx + 4);
    float v[8] = {v0.x, v0.y, v0.z, v0.w, v1.x, v1.y, v1.z, v1.w};
    half8_t hv, mv;
    float s = 0.f;
#pragma unroll
    for (int e = 0; e < 8; e++) {
        s += v[e] * v[e];
        _Float16 h = (_Float16)v[e];
        hv[e] = h;
        mv[e] = (_Float16)(v[e] - (float)h);
    }
    *(half8_t*)(hi + idx) = hv;
    *(half8_t*)(mid + idx) = mv;

    if (isW) {
        // one wave covers exactly one row of 512: reduce s across 64 lanes
#pragma unroll
        for (int o = 32; o > 0; o >>= 1) s += __shfl_down(s, o);
        if ((t & 63) == 0) {
            int row = (blk - 1024) * 4 + (t >> 6);
            w2[row] = s;
        }
    }
}

// ---------------------------------------------------------------------------
// MFMA score kernel: s[b,k] = w2[k] - 2*dot(X[b],W[k]) via 3-product f16
// hi/mid split. R8 structure (128x128 tile, BK=32, dbuf LDS, 1 barrier/iter)
// with PRODUCT-MAJOR MFMA ordering: all 16 am*bh, then 16 ah*bm, then 16
// ah*bh — consecutive MFMAs are independent (16 instrs between accumulator
// reuse) so each wave issues at pipe throughput instead of stalling on the
// RAW chain inside each (i,j) triple.
// ---------------------------------------------------------------------------
__global__ __launch_bounds__(256, 2) void score_kernel(
        const _Float16* __restrict__ Xhi, const _Float16* __restrict__ Xmi,
        const _Float16* __restrict__ Whi, const _Float16* __restrict__ Wmi,
        const float* __restrict__ w2,
        float* __restrict__ pval, int* __restrict__ pidx) {
    // 64 KB: two buffers, each Ah|Am|Bh|Bm (4096 f16 = 8KB each)
    __shared__ __align__(16) _Float16 lds[2][16384];

    const int t    = threadIdx.x;
    const int lane = t & 63;
    const int w    = t >> 6;        // wave 0..3
    const int wm   = w >> 1;        // wave m-half
    const int wn   = w & 1;         // wave n-half
    const int m0   = blockIdx.y * 128;
    const int n0   = blockIdx.x * 128;

    f32x4 acc[4][4];
#pragma unroll
    for (int i = 0; i < 4; i++)
#pragma unroll
        for (int j = 0; j < 4; j++) acc[i][j] = (f32x4){0.f, 0.f, 0.f, 0.f};

    // staging: wave w loads 16-row blocks (2w, 2w+1) of each of the 4 arrays.
    // within a 1KB block: lane l -> row (l&15), k-octet (l>>4).
    const int r16 = lane & 15;
    const int kg  = lane >> 4;
    const int b0  = 2 * w, b1 = 2 * w + 1;
    const size_t ko = (size_t)kg * 8;
    const _Float16* gA[4];
    const _Float16* gB[4];
    gA[0] = Xhi + (size_t)(m0 + b0 * 16 + r16) * DIMK + ko;
    gA[1] = Xhi + (size_t)(m0 + b1 * 16 + r16) * DIMK + ko;
    gA[2] = Xmi + (size_t)(m0 + b0 * 16 + r16) * DIMK + ko;
    gA[3] = Xmi + (size_t)(m0 + b1 * 16 + r16) * DIMK + ko;
    gB[0] = Whi + (size_t)(n0 + b0 * 16 + r16) * DIMK + ko;
    gB[1] = Whi + (size_t)(n0 + b1 * 16 + r16) * DIMK + ko;
    gB[2] = Wmi + (size_t)(n0 + b0 * 16 + r16) * DIMK + ko;
    gB[3] = Wmi + (size_t)(n0 + b1 * 16 + r16) * DIMK + ko;
    // LDS dest offsets (f16 units) within a buffer: Ah@0 Am@4096 Bh@8192 Bm@12288
    const int dA[4] = {b0 * 512, b1 * 512, 4096 + b0 * 512, 4096 + b1 * 512};
    const int dB[4] = {8192 + b0 * 512, 8192 + b1 * 512,
                       12288 + b0 * 512, 12288 + b1 * 512};

    // prologue: fill buffer 0 with tile k=0
#pragma unroll
    for (int p = 0; p < 4; p++) {
        GLD16(gA[p], &lds[0][dA[p]]);
        GLD16(gB[p], &lds[0][dB[p]]);
    }

    int cur = 0;
    for (int k0 = 0; k0 < DIMK; k0 += BK) {
        __syncthreads();               // lds[cur] staged; prior frag reads done
        if (k0 + BK < DIMK) {          // prefetch next tile into alternate buf
            int nk = k0 + BK;
#pragma unroll
            for (int p = 0; p < 4; p++) {
                GLD16(gA[p] + nk, &lds[cur ^ 1][dA[p]]);
                GLD16(gB[p] + nk, &lds[cur ^ 1][dB[p]]);
            }
        }
        const _Float16* sAh = &lds[cur][0];
        const _Float16* sAm = &lds[cur][4096];
        const _Float16* sBh = &lds[cur][8192];
        const _Float16* sBm = &lds[cur][12288];

        half8_t ah[4], am[4], bh[4], bm[4];
#pragma unroll
        for (int i = 0; i < 4; i++) {
            ah[i] = *(const half8_t*)(sAh + (wm * 4 + i) * 512 + lane * 8);
            am[i] = *(const half8_t*)(sAm + (wm * 4 + i) * 512 + lane * 8);
            bh[i] = *(const half8_t*)(sBh + (wn * 4 + i) * 512 + lane * 8);
            bm[i] = *(const half8_t*)(sBm + (wn * 4 + i) * 512 + lane * 8);
        }
        // product-major: consecutive MFMAs independent (16 between acc reuse)
#pragma unroll
        for (int i = 0; i < 4; i++)
#pragma unroll
            for (int j = 0; j < 4; j++)
                acc[i][j] = __builtin_amdgcn_mfma_f32_16x16x32_f16(am[i], bh[j], acc[i][j], 0, 0, 0);
#pragma unroll
        for (int i = 0; i < 4; i++)
#pragma unroll
            for (int j = 0; j < 4; j++)
                acc[i][j] = __builtin_amdgcn_mfma_f32_16x16x32_f16(ah[i], bm[j], acc[i][j], 0, 0, 0);
#pragma unroll
        for (int i = 0; i < 4; i++)
#pragma unroll
            for (int j = 0; j < 4; j++)
                acc[i][j] = __builtin_amdgcn_mfma_f32_16x16x32_f16(ah[i], bh[j], acc[i][j], 0, 0, 0);
        cur ^= 1;
    }

    // ---- per-row argmin over this wave's 64 cols ----
    // D layout: col = lane&15, row = (lane>>4)*4 + v   (m89/m91 verified)
    const int q  = lane >> 4;
    const int cl = lane & 15;
    float w2v[4];
    int   ncol[4];
#pragma unroll
    for (int j = 0; j < 4; j++) {
        ncol[j] = n0 + wn * 64 + j * 16 + cl;
        w2v[j]  = w2[ncol[j]];
    }
#pragma unroll
    for (int i = 0; i < 4; i++)
#pragma unroll
        for (int v = 0; v < 4; v++) {
            float bv = FLT_MAX;
            int   bi = 0x7FFFFFFF;
#pragma unroll
            for (int j = 0; j < 4; j++) {        // j ascending -> ties keep lower n
                float s = w2v[j] - 2.0f * acc[i][j][v];
                if (s < bv) { bv = s; bi = ncol[j]; }
            }
#pragma unroll
            for (int mask = 1; mask <= 8; mask <<= 1) {   // reduce over 16 col-lanes
                float ov = __shfl_xor(bv, mask);
                int   oi = __shfl_xor(bi, mask);
                if (ov < bv || (ov == bv && oi < bi)) { bv = ov; bi = oi; }
            }
            if (cl == 0) {
                int m = m0 + wm * 64 + i * 16 + q * 4 + v;
                int chunk = blockIdx.x * 2 + wn;
                pval[(size_t)m * NCHUNK + chunk] = bv;
                pidx[(size_t)m * NCHUNK + chunk] = bi;
            }
        }
}

// ---------------------------------------------------------------------------
// Final: reduce 64 partials/row -> BMU, separable Gaussian, write 4096 floats.
// ---------------------------------------------------------------------------
__global__ __launch_bounds__(256) void epilogue_kernel(
        const float* __restrict__ pval, const int* __restrict__ pidx,
        const int* __restrict__ decay_p, const int* __restrict__ it_p,
        float* __restrict__ out) {
    __shared__ float er[64];
    __shared__ float ec[64];
    __shared__ int   s_idx;
    const int b = blockIdx.x;
    const int t = threadIdx.x;

    if (t < 64) {
        float v  = pval[(size_t)b * NCHUNK + t];
        int   ii = pidx[(size_t)b * NCHUNK + t];
#pragma unroll
        for (int mask = 1; mask <= 32; mask <<= 1) {
            float ov = __shfl_xor(v, mask);
            int   oi = __shfl_xor(ii, mask);
            if (ov < v || (ov == v && oi < ii)) { v = ov; ii = oi; }
        }
        if (t == 0) s_idx = ii;
    }
    __syncthreads();
    const int r = s_idx >> 6;
    const int c = s_idx & 63;
    const float lr  = expf(-(float)(*it_p) / (float)(*decay_p));
    const float so  = 32.0f * lr;          // SIGMA = 32
    const float inv = 1.0f / (so * so);
    if (t < 64) {
        float d = (float)(t - r);
        er[t] = expf(-d * d * inv);
    } else if (t < 128) {
        int j = t - 64;
        float d = (float)(j - c);
        ec[j] = expf(-d * d * inv);
    }
    __syncthreads();
    float4* out4 = (float4*)(out + (size_t)b * 4096);
#pragma unroll
    for (int qq = 0; qq < 4; qq++) {
        int f  = t + 256 * qq;
        int i  = f >> 4;
        int j0 = (f & 15) * 4;
        float e = er[i];
        out4[f] = make_float4(e * ec[j0], e * ec[j0 + 1],
                              e * ec[j0 + 2], e * ec[j0 + 3]);
    }
}

// ---------------------------------------------------------------------------
extern "C" void kernel_launch(void* const* d_in, const int* in_sizes, int n_in,
                              void* d_out, int out_size, void* d_ws, size_t ws_size,
                              hipStream_t stream) {
    const float* X       = (const float*)d_in[0];   // [4096,512]
    const float* W       = (const float*)d_in[1];   // [4096,512]
    const int*   decay_p = (const int*)d_in[3];
    const int*   it_p    = (const int*)d_in[4];
    float* out = (float*)d_out;

    // ws: Xhi|Xmi|Whi|Wmi (4MB each f16) | w2 16KB | pval 1MB | pidx 1MB
    _Float16* Xhi = (_Float16*)d_ws;
    _Float16* Xmi = Xhi + (size_t)BATCH * DIMK;
    _Float16* Whi = Xmi + (size_t)BATCH * DIMK;
    _Float16* Wmi = Whi + (size_t)MN * DIMK;
    float*    w2  = (float*)(Wmi + (size_t)MN * DIMK);
    float*    pval = w2 + MN;
    int*      pidx = (int*)(pval + (size_t)BATCH * NCHUNK);

    convert_kernel<<<2048, 256, 0, stream>>>(X, W, Xhi, Xmi, Whi, Wmi, w2);
    score_kernel<<<dim3(32, 32), 256, 0, stream>>>(Xhi, Xmi, Whi, Wmi, w2, pval, pidx);
    epilogue_kernel<<<BATCH, 256, 0, stream>>>(pval, pidx, decay_p, it_p, out);
}